// Round 1
// 237.012 us; speedup vs baseline: 1.0498x; 1.0498x over previous
//
#include <hip/hip_runtime.h>
#include <hip/hip_bf16.h>
#include <math.h>

typedef __hip_bfloat16 bf16_t;
typedef __attribute__((ext_vector_type(8))) short short8;
typedef __attribute__((ext_vector_type(4))) float floatx4;

#define T_SEQ 2048
#define NB    4
#define NH    16
#define HD    64
#define C_DIM 1024
#define M_ROWS (NB * T_SEQ)   // 8192

// Q pre-scale: (1/sqrt(64)) * log2(e) so scores are in log2 units and
// P = exp2(s) directly (unnormalized softmax; shift cancels in O = sum(Pv)/sum(P)).
#define Q_SCALE 0.18033688011f

// ---------------------------------------------------------------- helpers
__device__ __forceinline__ void load_lds16(const bf16_t* g, bf16_t* l) {
    __builtin_amdgcn_global_load_lds(
        (const __attribute__((address_space(1))) void*)g,
        (__attribute__((address_space(3))) void*)l,
        16, 0, 0);
}

__device__ __forceinline__ floatx4 mfma16(short8 a, short8 b, floatx4 c) {
    return __builtin_amdgcn_mfma_f32_16x16x32_bf16(a, b, c, 0, 0, 0);
}

// ---------------------------------------------------------------- converts
__global__ void convert_x_kernel(const float* __restrict__ x, bf16_t* __restrict__ xb) {
    int i = blockIdx.x * 256 + threadIdx.x;   // one float4 per thread
    float4 v = reinterpret_cast<const float4*>(x)[i];
    union { bf16_t h[4]; short4 s4; } u;
    u.h[0] = __float2bfloat16(v.x);
    u.h[1] = __float2bfloat16(v.y);
    u.h[2] = __float2bfloat16(v.z);
    u.h[3] = __float2bfloat16(v.w);
    reinterpret_cast<short4*>(xb)[i] = u.s4;
}

// W [K,N] fp32 -> Wt [N,K] bf16, LDS-tiled transpose. block (32,8), grid (32,32,4)
__global__ void transpose_cvt_kernel(const float* __restrict__ W0, const float* __restrict__ W1,
                                     const float* __restrict__ W2, const float* __restrict__ W3,
                                     bf16_t* __restrict__ O0, bf16_t* __restrict__ O1,
                                     bf16_t* __restrict__ O2, bf16_t* __restrict__ O3) {
    const float* W = (blockIdx.z == 0) ? W0 : (blockIdx.z == 1) ? W1 : (blockIdx.z == 2) ? W2 : W3;
    bf16_t*      O = (blockIdx.z == 0) ? O0 : (blockIdx.z == 1) ? O1 : (blockIdx.z == 2) ? O2 : O3;
    __shared__ float tile[32][33];
    int bx = blockIdx.x * 32, by = blockIdx.y * 32;
    int tx = threadIdx.x, ty = threadIdx.y;
#pragma unroll
    for (int j = 0; j < 32; j += 8)
        tile[ty + j][tx] = W[(size_t)(by + ty + j) * C_DIM + bx + tx];
    __syncthreads();
#pragma unroll
    for (int j = 0; j < 32; j += 8)
        O[(size_t)(bx + ty + j) * C_DIM + by + tx] = __float2bfloat16(tile[tx][ty + j]);
}

// ---------------------------------------------------------------- GEMM mainloop
// C[128,128] += A[128,K] * Bt[128,K]^T  (both row-major, K-contiguous), BK=64.
// LDS layout XOR-swizzled: 16B piece p of row r lives at piece slot (p ^ (r&7)).
__device__ __forceinline__ void gemm_mainloop(const bf16_t* __restrict__ Ablk,
                                              const bf16_t* __restrict__ Bblk,
                                              bf16_t* As, bf16_t* Bs,
                                              floatx4 acc[4][4], int wave, int lane) {
    int lr = lane & 15, lq = lane >> 4;
    int wr = (wave >> 1) * 64, wc = (wave & 1) * 64;
    for (int kt = 0; kt < C_DIM; kt += 64) {
#pragma unroll
        for (int j = 0; j < 4; ++j) {
            int chunk = j * 256 + wave * 64 + lane;       // 0..1023, wave-contiguous
            int r = chunk >> 3, ps = chunk & 7;
            int c = ((ps ^ (r & 7)) * 8);                 // swizzled source column
            load_lds16(Ablk + (size_t)r * C_DIM + kt + c, As + chunk * 8);
            load_lds16(Bblk + (size_t)r * C_DIM + kt + c, Bs + chunk * 8);
        }
        __syncthreads();
#pragma unroll
        for (int kk = 0; kk < 2; ++kk) {
            short8 af[4], bfr[4];
            int psw = ((kk * 4 + lq) ^ (lr & 7)) * 8;     // swizzled piece offset
#pragma unroll
            for (int m = 0; m < 4; ++m)
                af[m] = *reinterpret_cast<const short8*>(As + (wr + m * 16 + lr) * 64 + psw);
#pragma unroll
            for (int n = 0; n < 4; ++n)
                bfr[n] = *reinterpret_cast<const short8*>(Bs + (wc + n * 16 + lr) * 64 + psw);
#pragma unroll
            for (int m = 0; m < 4; ++m)
#pragma unroll
                for (int n = 0; n < 4; ++n)
                    acc[m][n] = mfma16(af[m], bfr[n], acc[m][n]);
        }
        __syncthreads();
    }
}

// ---------------------------------------------------------------- QKV GEMM
// grid (8, 64, 3). Block->tile mapping is XCD-swizzled: f = x + 8y + 512z,
// xcd = f&7 owns row-panels [8*xcd, 8*xcd+8). Within an XCD, the A-panel
// index cycles FASTEST -> A (2 MB) stays L2-resident, W panels stream once.
__global__ __launch_bounds__(256, 3) void gemm_qkv_kernel(
    const bf16_t* __restrict__ xb,
    const bf16_t* __restrict__ WqT, const bf16_t* __restrict__ WkT, const bf16_t* __restrict__ WvT,
    const float* __restrict__ bq, const float* __restrict__ bk, const float* __restrict__ bv,
    bf16_t* __restrict__ Q, bf16_t* __restrict__ K, bf16_t* __restrict__ Vt) {
    __shared__ bf16_t As[128 * 64];
    __shared__ bf16_t Bs[128 * 64];
    int tid = threadIdx.x, wave = tid >> 6, lane = tid & 63;

    int f    = (int)blockIdx.x + ((int)blockIdx.y << 3) + ((int)blockIdx.z << 9);
    int xcd  = f & 7;
    int s    = f >> 3;          // 0..191 per-XCD sequence
    int rloc = s & 7;           // A-panel: fastest
    int t2   = s >> 3;          // 0..23
    int colp = t2 & 7;          // W-panel
    int wsel = t2 >> 3;         // 0..2: z outermost per XCD
    int row0 = (xcd * 8 + rloc) * 128;
    int col0 = colp * 128;

    const bf16_t* Wt  = (wsel == 0) ? WqT : (wsel == 1) ? WkT : WvT;
    const float* bias = (wsel == 0) ? bq : (wsel == 1) ? bk : bv;

    floatx4 acc[4][4] = {};
    gemm_mainloop(xb + (size_t)row0 * C_DIM, Wt + (size_t)col0 * C_DIM, As, Bs, acc, wave, lane);

    int lr = lane & 15, lq = lane >> 4;
    int wr = (wave >> 1) * 64, wc = (wave & 1) * 64;

    if (wsel == 2) {
        // V transposed store, packed short4 (8B)
#pragma unroll
        for (int nt = 0; nt < 4; ++nt) {
            int col = col0 + wc + nt * 16 + lr;
            float bvv = bias[col];
            int h = col >> 6, d = col & 63;
#pragma unroll
            for (int m = 0; m < 4; ++m) {
                int rowg0 = row0 + wr + m * 16 + lq * 4;
                int b = rowg0 >> 11, t0 = rowg0 & (T_SEQ - 1);
                union { bf16_t h4[4]; short4 s4; } u;
#pragma unroll
                for (int r = 0; r < 4; ++r)
                    u.h4[r] = __float2bfloat16(acc[m][nt][r] + bvv);
                *reinterpret_cast<short4*>(
                    &Vt[((size_t)((b * NH + h) * HD + d)) * T_SEQ + t0]) = u.s4;
            }
        }
    } else {
        float scale = (wsel == 0) ? Q_SCALE : 1.0f;
        bf16_t* outp = (wsel == 0) ? Q : K;
#pragma unroll
        for (int nt = 0; nt < 4; ++nt) {
            int col = col0 + wc + nt * 16 + lr;
            float bvv = bias[col];
            int h = col >> 6, d = col & 63;
#pragma unroll
            for (int m = 0; m < 4; ++m) {
#pragma unroll
                for (int r = 0; r < 4; ++r) {
                    int rowg = row0 + wr + m * 16 + lq * 4 + r;
                    int b = rowg >> 11, t = rowg & (T_SEQ - 1);
                    float val = (acc[m][nt][r] + bvv) * scale;
                    outp[((size_t)((b * NH + h) * T_SEQ + t)) * HD + d] =
                        __float2bfloat16(val);
                }
            }
        }
    }
}

// ---------------------------------------------------------------- attention
// grid (8, 64), block 256 threads = 4 waves; each wave owns 32 q-rows.
// (Round-8 change: was 8 waves x 16 q-rows. The kernel is LDS-pipe-bound:
// each wave reads the full 8KB K tile + 8KB V tile as fragments regardless
// of how many q-rows it owns, so 32 q-rows/wave halves K/V LDS bytes per
// q*k pair: 20B -> 12B. Predicted MfmaUtil 21% -> ~35%.)
// XCD-local heads: under round-robin dispatch xcd = blockIdx.x, and we map
// bh = 8*xcd + (y&7) so each XCD's K+V working set is 8 heads = 4 MB = its
// L2. qp = y>>3 gives the uniform pass pair (15-qp, qp) = 34 iterations for
// every block.
// VALU diet: native v_exp_f32 via __builtin_amdgcn_exp2f and truncation-
// to-bf16 for the P store (trunc of P in [0,1] is within bf16 noise).
__global__ __launch_bounds__(256, 2) void attn_kernel(
    const bf16_t* __restrict__ Q, const bf16_t* __restrict__ K,
    const bf16_t* __restrict__ Vt, bf16_t* __restrict__ ctx) {
    __shared__ __align__(16) bf16_t Ks[2][64 * 64];       // K tile  [k][d], swizzled
    __shared__ __align__(16) bf16_t Vs[2][64 * 64];       // Vt tile [d][k], swizzled
    __shared__ __align__(16) unsigned short Ps[128 * 64]; // P tile [q][k], swizzled
    int tid = threadIdx.x, w = tid >> 6, lane = tid & 63;
    int lr = lane & 15, lq = lane >> 4;
    int xcd = (int)blockIdx.x;
    int y   = (int)blockIdx.y;
    int bh  = xcd * 8 + (y & 7);      // XCD-local head group
    int qp  = y >> 3;                 // 0..7 pass pair
    int b = bh >> 4, h = bh & 15;

    const bf16_t* Kbase = K  + (size_t)bh * T_SEQ * HD;
    const bf16_t* Vbase = Vt + (size_t)bh * HD * T_SEQ;

#pragma unroll 1
    for (int pass = 0; pass < 2; ++pass) {
        int qt = pass ? qp : (15 - qp);
        int q0 = qt * 128;
        int ktiles = 2 * qt + 2;                      // always even
        const bf16_t* Qbase = Q + ((size_t)bh * T_SEQ + q0) * HD;

        // stage tile 0 into buffer 0 (256 threads: 2 chunks each for K and V).
        // Safe vs pass-0 stragglers: their last iteration reads buffer 1.
#pragma unroll
        for (int cc = 0; cc < 2; ++cc) {
            int ch = tid + cc * 256;
            int r = ch >> 3, ps = ch & 7;
            int c = ((ps ^ (r & 7)) * 8);
            load_lds16(Kbase + (size_t)r * HD + c, Ks[0] + ch * 8);
            load_lds16(Vbase + (size_t)r * T_SEQ + c, Vs[0] + ch * 8);
        }

        // Q fragments in registers: wave w owns rows [w*32, w*32+32)
        short8 qf[2][2];
#pragma unroll
        for (int g = 0; g < 2; ++g)
#pragma unroll
            for (int kk = 0; kk < 2; ++kk)
                qf[g][kk] = *reinterpret_cast<const short8*>(
                    Qbase + (size_t)(w * 32 + g * 16 + lr) * HD + kk * 32 + lq * 8);

        floatx4 o[2][4] = {};
        float lpart[2][4] = {};
        int buf = 0;

        for (int it = 0; it < ktiles; ++it) {
            int kt0 = it * 64;
            __syncthreads();   // drains stage(it) vmcnt; protects both buffers

            // prefetch next tile — drains at NEXT barrier (overlaps this compute)
            if (it + 1 < ktiles) {
                int nk0 = kt0 + 64;
#pragma unroll
                for (int cc = 0; cc < 2; ++cc) {
                    int ch = tid + cc * 256;
                    int r = ch >> 3, ps = ch & 7;
                    int c = ((ps ^ (r & 7)) * 8);
                    load_lds16(Kbase + (size_t)(nk0 + r) * HD + c, Ks[buf ^ 1] + ch * 8);
                    load_lds16(Vbase + (size_t)r * T_SEQ + nk0 + c, Vs[buf ^ 1] + ch * 8);
                }
            }

            const bf16_t* Kc = Ks[buf];
            const bf16_t* Vc = Vs[buf];

            // S = Q K^T (log2 units): K fragments read ONCE, reused by both
            // 16-row q groups.
            floatx4 s[2][4] = {};
            short8 kf[4][2];
#pragma unroll
            for (int kk = 0; kk < 2; ++kk) {
                int psw = ((kk * 4 + lq) ^ (lr & 7)) * 8;
#pragma unroll
                for (int n = 0; n < 4; ++n)
                    kf[n][kk] = *reinterpret_cast<const short8*>(Kc + (n * 16 + lr) * 64 + psw);
            }
#pragma unroll
            for (int g = 0; g < 2; ++g)
#pragma unroll
                for (int kk = 0; kk < 2; ++kk)
#pragma unroll
                    for (int n = 0; n < 4; ++n)
                        s[g][n] = mfma16(qf[g][kk], kf[n][kk], s[g][n]);

            // causal mask only on the last two tiles (block-uniform branch)
            if (it >= ktiles - 2) {
#pragma unroll
                for (int g = 0; g < 2; ++g)
#pragma unroll
                    for (int r = 0; r < 4; ++r) {
                        int rowg = q0 + w * 32 + g * 16 + lq * 4 + r;
#pragma unroll
                        for (int n = 0; n < 4; ++n) {
                            int colg = kt0 + n * 16 + lr;
                            if (colg > rowg) s[g][n][r] = -1e30f;
                        }
                    }
            }

            // P = exp2(s): single v_exp_f32 each; per-lane l partials
#pragma unroll
            for (int g = 0; g < 2; ++g) {
#pragma unroll
                for (int n = 0; n < 4; ++n)
#pragma unroll
                    for (int r = 0; r < 4; ++r)
                        s[g][n][r] = __builtin_amdgcn_exp2f(s[g][n][r]);
#pragma unroll
                for (int r = 0; r < 4; ++r)
                    lpart[g][r] += (s[g][0][r] + s[g][1][r]) + (s[g][2][r] + s[g][3][r]);
            }

            // dump P to LDS (C-layout -> A-layout; rows wave-private, trunc cvt)
#pragma unroll
            for (int g = 0; g < 2; ++g)
#pragma unroll
                for (int n = 0; n < 4; ++n)
#pragma unroll
                    for (int r = 0; r < 4; ++r) {
                        int prow = w * 32 + g * 16 + lq * 4 + r;
                        int piece = n * 2 + (lr >> 3);
                        union { float f; unsigned u; } cv; cv.f = s[g][n][r];
                        Ps[prow * 64 + ((piece ^ (prow & 7)) * 8) + (lr & 7)] =
                            (unsigned short)(cv.u >> 16);
                    }

            // O += P V : V fragments read ONCE, reused by both q groups
            short8 pf[2][2], vf[4][2];
#pragma unroll
            for (int g = 0; g < 2; ++g)
#pragma unroll
                for (int kk = 0; kk < 2; ++kk) {
                    int prow = w * 32 + g * 16 + lr;
                    pf[g][kk] = *reinterpret_cast<const short8*>(
                        Ps + prow * 64 + (((kk * 4 + lq) ^ (lr & 7)) * 8));
                }
#pragma unroll
            for (int kk = 0; kk < 2; ++kk) {
                int psw = ((kk * 4 + lq) ^ (lr & 7)) * 8;
#pragma unroll
                for (int dt = 0; dt < 4; ++dt)
                    vf[dt][kk] = *reinterpret_cast<const short8*>(Vc + (dt * 16 + lr) * 64 + psw);
            }
#pragma unroll
            for (int g = 0; g < 2; ++g)
#pragma unroll
                for (int kk = 0; kk < 2; ++kk)
#pragma unroll
                    for (int dt = 0; dt < 4; ++dt)
                        o[g][dt] = mfma16(pf[g][kk], vf[dt][kk], o[g][dt]);

            buf ^= 1;
        }

        // epilogue: reduce l across the 16 col-lanes (lane bits 0-3), normalize
#pragma unroll
        for (int g = 0; g < 2; ++g)
#pragma unroll
            for (int r = 0; r < 4; ++r) {
                float l = lpart[g][r];
                l += __shfl_xor(l, 1);
                l += __shfl_xor(l, 2);
                l += __shfl_xor(l, 4);
                l += __shfl_xor(l, 8);
                float inv = 1.0f / l;
                int t = q0 + w * 32 + g * 16 + lq * 4 + r;
#pragma unroll
                for (int dt = 0; dt < 4; ++dt) {
                    int d = dt * 16 + lr;
                    ctx[((size_t)(b * T_SEQ + t)) * C_DIM + h * HD + d] =
                        __float2bfloat16(o[g][dt][r] * inv);
                }
            }
    }
}

// ---------------------------------------------------------------- output GEMM
// grid (8, 64), XCD-swizzled like gemm_qkv.
__global__ __launch_bounds__(256, 3) void gemm_out_kernel(
    const bf16_t* __restrict__ Actx, const bf16_t* __restrict__ WoT,
    const float* __restrict__ bo, float* __restrict__ out) {
    __shared__ bf16_t As[128 * 64];
    __shared__ bf16_t Bs[128 * 64];
    int tid = threadIdx.x, wave = tid >> 6, lane = tid & 63;

    int f    = (int)blockIdx.x + ((int)blockIdx.y << 3);
    int xcd  = f & 7;
    int s    = f >> 3;          // 0..63
    int rloc = s & 7;           // A-panel: fastest
    int colp = s >> 3;          // 0..7
    int row0 = (xcd * 8 + rloc) * 128;
    int col0 = colp * 128;

    floatx4 acc[4][4] = {};
    gemm_mainloop(Actx + (size_t)row0 * C_DIM, WoT + (size_t)col0 * C_DIM, As, Bs, acc, wave, lane);
    int lr = lane & 15, lq = lane >> 4;
    int wr = (wave >> 1) * 64, wc = (wave & 1) * 64;
#pragma unroll
    for (int nt = 0; nt < 4; ++nt) {
        int col = col0 + wc + nt * 16 + lr;
        float bvv = bo[col];
#pragma unroll
        for (int m = 0; m < 4; ++m)
#pragma unroll
            for (int r = 0; r < 4; ++r) {
                int rowg = row0 + wr + m * 16 + lq * 4 + r;
                out[(size_t)rowg * C_DIM + col] = acc[m][nt][r] + bvv;
            }
    }
}

// ---------------------------------------------------------------- launcher
extern "C" void kernel_launch(void* const* d_in, const int* in_sizes, int n_in,
                              void* d_out, int out_size, void* d_ws, size_t ws_size,
                              hipStream_t stream) {
    const float* x  = (const float*)d_in[0];
    const float* Wq = (const float*)d_in[1];
    const float* bq = (const float*)d_in[2];
    const float* Wk = (const float*)d_in[3];
    const float* bk = (const float*)d_in[4];
    const float* Wv = (const float*)d_in[5];
    const float* bv = (const float*)d_in[6];
    const float* Wo = (const float*)d_in[7];
    const float* bo = (const float*)d_in[8];
    float* out = (float*)d_out;

    char* ws = (char*)d_ws;
    bf16_t* xb  = (bf16_t*)ws; ws += (size_t)M_ROWS * C_DIM * 2;   // 16 MB
    bf16_t* WqT = (bf16_t*)ws; ws += (size_t)C_DIM * C_DIM * 2;    //  2 MB
    bf16_t* WkT = (bf16_t*)ws; ws += (size_t)C_DIM * C_DIM * 2;
    bf16_t* WvT = (bf16_t*)ws; ws += (size_t)C_DIM * C_DIM * 2;
    bf16_t* WoT = (bf16_t*)ws; ws += (size_t)C_DIM * C_DIM * 2;
    bf16_t* Qb  = (bf16_t*)ws; ws += (size_t)M_ROWS * C_DIM * 2;   // [B,H,T,D]
    bf16_t* Kb  = (bf16_t*)ws; ws += (size_t)M_ROWS * C_DIM * 2;   // [B,H,T,D]
    bf16_t* Vtb = (bf16_t*)ws; ws += (size_t)M_ROWS * C_DIM * 2;   // [B,H,D,T]
    bf16_t* ctx = (bf16_t*)ws; ws += (size_t)M_ROWS * C_DIM * 2;   // [B,T,C]

    convert_x_kernel<<<(M_ROWS * C_DIM / 4) / 256, 256, 0, stream>>>(x, xb);
    transpose_cvt_kernel<<<dim3(32, 32, 4), dim3(32, 8), 0, stream>>>(
        Wq, Wk, Wv, Wo, WqT, WkT, WvT, WoT);
    gemm_qkv_kernel<<<dim3(8, 64, 3), 256, 0, stream>>>(
        xb, WqT, WkT, WvT, bq, bk, bv, Qb, Kb, Vtb);
    attn_kernel<<<dim3(8, 64), 256, 0, stream>>>(Qb, Kb, Vtb, ctx);
    gemm_out_kernel<<<dim3(8, 64), 256, 0, stream>>>(ctx, WoT, bo, out);
}

// Round 2
// 230.891 us; speedup vs baseline: 1.0777x; 1.0265x over previous
//
#include <hip/hip_runtime.h>
#include <hip/hip_bf16.h>
#include <math.h>

typedef __hip_bfloat16 bf16_t;
typedef __attribute__((ext_vector_type(8))) short short8;
typedef __attribute__((ext_vector_type(4))) float floatx4;

#define T_SEQ 2048
#define NB    4
#define NH    16
#define HD    64
#define C_DIM 1024
#define M_ROWS (NB * T_SEQ)   // 8192

// Q pre-scale: (1/sqrt(64)) * log2(e) so scores are in log2 units and
// P = exp2(s) directly (unnormalized softmax; shift cancels in O = sum(Pv)/sum(P)).
#define Q_SCALE 0.18033688011f

// ---------------------------------------------------------------- helpers
__device__ __forceinline__ void load_lds16(const bf16_t* g, bf16_t* l) {
    __builtin_amdgcn_global_load_lds(
        (const __attribute__((address_space(1))) void*)g,
        (__attribute__((address_space(3))) void*)l,
        16, 0, 0);
}

__device__ __forceinline__ floatx4 mfma16(short8 a, short8 b, floatx4 c) {
    return __builtin_amdgcn_mfma_f32_16x16x32_bf16(a, b, c, 0, 0, 0);
}

// ---------------------------------------------------------------- converts
__global__ void convert_x_kernel(const float* __restrict__ x, bf16_t* __restrict__ xb) {
    int i = blockIdx.x * 256 + threadIdx.x;   // one float4 per thread
    float4 v = reinterpret_cast<const float4*>(x)[i];
    union { bf16_t h[4]; short4 s4; } u;
    u.h[0] = __float2bfloat16(v.x);
    u.h[1] = __float2bfloat16(v.y);
    u.h[2] = __float2bfloat16(v.z);
    u.h[3] = __float2bfloat16(v.w);
    reinterpret_cast<short4*>(xb)[i] = u.s4;
}

// W [K,N] fp32 -> Wt [N,K] bf16, LDS-tiled transpose. block (32,8), grid (32,32,4)
__global__ void transpose_cvt_kernel(const float* __restrict__ W0, const float* __restrict__ W1,
                                     const float* __restrict__ W2, const float* __restrict__ W3,
                                     bf16_t* __restrict__ O0, bf16_t* __restrict__ O1,
                                     bf16_t* __restrict__ O2, bf16_t* __restrict__ O3) {
    const float* W = (blockIdx.z == 0) ? W0 : (blockIdx.z == 1) ? W1 : (blockIdx.z == 2) ? W2 : W3;
    bf16_t*      O = (blockIdx.z == 0) ? O0 : (blockIdx.z == 1) ? O1 : (blockIdx.z == 2) ? O2 : O3;
    __shared__ float tile[32][33];
    int bx = blockIdx.x * 32, by = blockIdx.y * 32;
    int tx = threadIdx.x, ty = threadIdx.y;
#pragma unroll
    for (int j = 0; j < 32; j += 8)
        tile[ty + j][tx] = W[(size_t)(by + ty + j) * C_DIM + bx + tx];
    __syncthreads();
#pragma unroll
    for (int j = 0; j < 32; j += 8)
        O[(size_t)(bx + ty + j) * C_DIM + by + tx] = __float2bfloat16(tile[tx][ty + j]);
}

// ---------------------------------------------------------------- GEMM mainloop
// C[128,128] += A[128,K] * Bt[128,K]^T  (both row-major, K-contiguous), BK=64.
// LDS layout XOR-swizzled: 16B piece p of row r lives at piece slot (p ^ (r&7)).
__device__ __forceinline__ void gemm_mainloop(const bf16_t* __restrict__ Ablk,
                                              const bf16_t* __restrict__ Bblk,
                                              bf16_t* As, bf16_t* Bs,
                                              floatx4 acc[4][4], int wave, int lane) {
    int lr = lane & 15, lq = lane >> 4;
    int wr = (wave >> 1) * 64, wc = (wave & 1) * 64;
    for (int kt = 0; kt < C_DIM; kt += 64) {
#pragma unroll
        for (int j = 0; j < 4; ++j) {
            int chunk = j * 256 + wave * 64 + lane;       // 0..1023, wave-contiguous
            int r = chunk >> 3, ps = chunk & 7;
            int c = ((ps ^ (r & 7)) * 8);                 // swizzled source column
            load_lds16(Ablk + (size_t)r * C_DIM + kt + c, As + chunk * 8);
            load_lds16(Bblk + (size_t)r * C_DIM + kt + c, Bs + chunk * 8);
        }
        __syncthreads();
#pragma unroll
        for (int kk = 0; kk < 2; ++kk) {
            short8 af[4], bfr[4];
            int psw = ((kk * 4 + lq) ^ (lr & 7)) * 8;     // swizzled piece offset
#pragma unroll
            for (int m = 0; m < 4; ++m)
                af[m] = *reinterpret_cast<const short8*>(As + (wr + m * 16 + lr) * 64 + psw);
#pragma unroll
            for (int n = 0; n < 4; ++n)
                bfr[n] = *reinterpret_cast<const short8*>(Bs + (wc + n * 16 + lr) * 64 + psw);
#pragma unroll
            for (int m = 0; m < 4; ++m)
#pragma unroll
                for (int n = 0; n < 4; ++n)
                    acc[m][n] = mfma16(af[m], bfr[n], acc[m][n]);
        }
        __syncthreads();
    }
}

// ---------------------------------------------------------------- QKV GEMM
// grid (8, 64, 3). Block->tile mapping is XCD-swizzled: f = x + 8y + 512z,
// xcd = f&7 owns row-panels [8*xcd, 8*xcd+8). Within an XCD, the A-panel
// index cycles FASTEST -> A (2 MB) stays L2-resident, W panels stream once.
__global__ __launch_bounds__(256, 3) void gemm_qkv_kernel(
    const bf16_t* __restrict__ xb,
    const bf16_t* __restrict__ WqT, const bf16_t* __restrict__ WkT, const bf16_t* __restrict__ WvT,
    const float* __restrict__ bq, const float* __restrict__ bk, const float* __restrict__ bv,
    bf16_t* __restrict__ Q, bf16_t* __restrict__ K, bf16_t* __restrict__ Vt) {
    __shared__ bf16_t As[128 * 64];
    __shared__ bf16_t Bs[128 * 64];
    int tid = threadIdx.x, wave = tid >> 6, lane = tid & 63;

    int f    = (int)blockIdx.x + ((int)blockIdx.y << 3) + ((int)blockIdx.z << 9);
    int xcd  = f & 7;
    int s    = f >> 3;          // 0..191 per-XCD sequence
    int rloc = s & 7;           // A-panel: fastest
    int t2   = s >> 3;          // 0..23
    int colp = t2 & 7;          // W-panel
    int wsel = t2 >> 3;         // 0..2: z outermost per XCD
    int row0 = (xcd * 8 + rloc) * 128;
    int col0 = colp * 128;

    const bf16_t* Wt  = (wsel == 0) ? WqT : (wsel == 1) ? WkT : WvT;
    const float* bias = (wsel == 0) ? bq : (wsel == 1) ? bk : bv;

    floatx4 acc[4][4] = {};
    gemm_mainloop(xb + (size_t)row0 * C_DIM, Wt + (size_t)col0 * C_DIM, As, Bs, acc, wave, lane);

    int lr = lane & 15, lq = lane >> 4;
    int wr = (wave >> 1) * 64, wc = (wave & 1) * 64;

    if (wsel == 2) {
        // V transposed store, packed short4 (8B)
#pragma unroll
        for (int nt = 0; nt < 4; ++nt) {
            int col = col0 + wc + nt * 16 + lr;
            float bvv = bias[col];
            int h = col >> 6, d = col & 63;
#pragma unroll
            for (int m = 0; m < 4; ++m) {
                int rowg0 = row0 + wr + m * 16 + lq * 4;
                int b = rowg0 >> 11, t0 = rowg0 & (T_SEQ - 1);
                union { bf16_t h4[4]; short4 s4; } u;
#pragma unroll
                for (int r = 0; r < 4; ++r)
                    u.h4[r] = __float2bfloat16(acc[m][nt][r] + bvv);
                *reinterpret_cast<short4*>(
                    &Vt[((size_t)((b * NH + h) * HD + d)) * T_SEQ + t0]) = u.s4;
            }
        }
    } else {
        float scale = (wsel == 0) ? Q_SCALE : 1.0f;
        bf16_t* outp = (wsel == 0) ? Q : K;
#pragma unroll
        for (int nt = 0; nt < 4; ++nt) {
            int col = col0 + wc + nt * 16 + lr;
            float bvv = bias[col];
            int h = col >> 6, d = col & 63;
#pragma unroll
            for (int m = 0; m < 4; ++m) {
#pragma unroll
                for (int r = 0; r < 4; ++r) {
                    int rowg = row0 + wr + m * 16 + lq * 4 + r;
                    int b = rowg >> 11, t = rowg & (T_SEQ - 1);
                    float val = (acc[m][nt][r] + bvv) * scale;
                    outp[((size_t)((b * NH + h) * T_SEQ + t)) * HD + d] =
                        __float2bfloat16(val);
                }
            }
        }
    }
}

// ---------------------------------------------------------------- attention
// grid (8, 64), block 256 = 4 waves; wave owns 32 q-rows of a 128-row q-tile.
//
// Round-9 change: P never touches LDS. QK^T is computed SWAPPED —
// s = mfma(kf, qf) = S^T — so each lane holds P[q = lane&15][16 k-values]
// (k = n*16 + lq*4 + r). The PV A-fragment (lane needs P[q=lane&15]
// [k = kk*32 + lq*8 + 0..7]) is built fully in registers:
//   v_cvt_pk_bf16_f32 packs r-pairs, then per register pair (n,n+1):
//   v_permlane32_swap + v_permlane16_swap redistribute the four 16-lane
//   groups (all-to-all on lq; position-in-group = q is preserved).
// This removes 32 ds_write_b16 + 4 ds_read_b128 per wave-sub-iter (~55% of
// LDS-pipe cycles) and the write->read LDS latency link in the serial
// chain (R1 post-mortem: R0 was 100% LDS-pipe-saturated; R1 = 70% but
// latency-exposed). Freed Ps LDS goes to 128-wide k-tiles -> half the
// barriers (17/block vs 34). Softmax denom: lane-local sum + 2 shfl_xor.
__global__ __launch_bounds__(256, 2) void attn_kernel(
    const bf16_t* __restrict__ Q, const bf16_t* __restrict__ K,
    const bf16_t* __restrict__ Vt, bf16_t* __restrict__ ctx) {
    __shared__ __align__(16) bf16_t Ks[2][128 * 64];      // K tile [k][d], swizzled
    __shared__ __align__(16) bf16_t Vs[2][64 * 128];      // Vt tile [d][k], swizzled
    int tid = threadIdx.x, w = tid >> 6, lane = tid & 63;
    int lr = lane & 15, lq = lane >> 4;
    int xcd = (int)blockIdx.x;
    int y   = (int)blockIdx.y;
    int bh  = xcd * 8 + (y & 7);      // XCD-local head group
    int qp  = y >> 3;                 // 0..7 pass pair
    int b = bh >> 4, h = bh & 15;

    const bf16_t* Kbase = K  + (size_t)bh * T_SEQ * HD;
    const bf16_t* Vbase = Vt + (size_t)bh * HD * T_SEQ;

    int buf = 0;   // carried across passes: ktiles parity varies now
#pragma unroll 1
    for (int pass = 0; pass < 2; ++pass) {
        int qt = pass ? qp : (15 - qp);
        int q0 = qt * 128;
        int ktiles = qt + 1;                       // 128-wide k tiles
        const bf16_t* Qbase = Q + ((size_t)bh * T_SEQ + q0) * HD;

        // stage tile 0 into current buf. Safe vs stragglers: the previous
        // pass's last iteration read buf^1 (buf toggles after every iter),
        // and reads of this buf completed before that iteration's barrier.
        {
            int kt0s = 0;
#pragma unroll
            for (int cc = 0; cc < 4; ++cc) {
                int ch = tid + cc * 256;
                int r = ch >> 3, ps = ch & 7;
                int c = (ps ^ (r & 7)) * 8;
                load_lds16(Kbase + (size_t)(kt0s + r) * HD + c, Ks[buf] + ch * 8);
                int rv = ch >> 4, pv = ch & 15;
                int cv = (pv ^ (rv & 7)) * 8;
                load_lds16(Vbase + (size_t)rv * T_SEQ + kt0s + cv, Vs[buf] + ch * 8);
            }
        }

        // Q fragments in registers: wave w owns rows [w*32, w*32+32)
        short8 qf[2][2];
#pragma unroll
        for (int g = 0; g < 2; ++g)
#pragma unroll
            for (int kk = 0; kk < 2; ++kk)
                qf[g][kk] = *reinterpret_cast<const short8*>(
                    Qbase + (size_t)(w * 32 + g * 16 + lr) * HD + kk * 32 + lq * 8);

        floatx4 o[2][4] = {};
        float lpart[2] = {0.f, 0.f};

        for (int it = 0; it < ktiles; ++it) {
            __syncthreads();   // drains stage(it) vmcnt; protects both buffers

            // prefetch next 128-k tile — drains at NEXT barrier
            if (it + 1 < ktiles) {
                int nk0 = (it + 1) * 128;
#pragma unroll
                for (int cc = 0; cc < 4; ++cc) {
                    int ch = tid + cc * 256;
                    int r = ch >> 3, ps = ch & 7;
                    int c = (ps ^ (r & 7)) * 8;
                    load_lds16(Kbase + (size_t)(nk0 + r) * HD + c, Ks[buf ^ 1] + ch * 8);
                    int rv = ch >> 4, pv = ch & 15;
                    int cv = (pv ^ (rv & 7)) * 8;
                    load_lds16(Vbase + (size_t)rv * T_SEQ + nk0 + cv, Vs[buf ^ 1] + ch * 8);
                }
            }

            const bf16_t* Kc = Ks[buf];
            const bf16_t* Vc = Vs[buf];
            bool last = (it == ktiles - 1);        // block-uniform

#pragma unroll
            for (int sub = 0; sub < 2; ++sub) {
                int ktb = it * 128 + sub * 64;

                // S^T = K Q^T (log2 units). Lane holds S[q=lr][k=n*16+lq*4+r].
                floatx4 s[2][4] = {};
                {
                    short8 kf[4][2];
#pragma unroll
                    for (int kk = 0; kk < 2; ++kk) {
                        int psw = ((kk * 4 + lq) ^ (lr & 7)) * 8;
#pragma unroll
                        for (int n = 0; n < 4; ++n)
                            kf[n][kk] = *reinterpret_cast<const short8*>(
                                Kc + (sub * 64 + n * 16 + lr) * 64 + psw);
                    }
#pragma unroll
                    for (int g = 0; g < 2; ++g)
#pragma unroll
                        for (int kk = 0; kk < 2; ++kk)
#pragma unroll
                            for (int n = 0; n < 4; ++n)
                                s[g][n] = mfma16(kf[n][kk], qf[g][kk], s[g][n]);
                }

                // causal mask on the last 128-k tile only
                if (last) {
#pragma unroll
                    for (int g = 0; g < 2; ++g) {
                        int rowg = q0 + w * 32 + g * 16 + lr;      // q (lane-local)
#pragma unroll
                        for (int n = 0; n < 4; ++n)
#pragma unroll
                            for (int r = 0; r < 4; ++r) {
                                int colg = ktb + n * 16 + lq * 4 + r;  // k
                                if (colg > rowg) s[g][n][r] = -1e30f;
                            }
                    }
                }

                // per g: exp2, lane-local l partial, pack + permlane -> pf
                short8 pf[2][2];
#pragma unroll
                for (int g = 0; g < 2; ++g) {
#pragma unroll
                    for (int n = 0; n < 4; ++n)
#pragma unroll
                        for (int r = 0; r < 4; ++r)
                            s[g][n][r] = __builtin_amdgcn_exp2f(s[g][n][r]);
                    float p0 = (s[g][0][0] + s[g][0][1]) + (s[g][0][2] + s[g][0][3]);
                    float p1 = (s[g][1][0] + s[g][1][1]) + (s[g][1][2] + s[g][1][3]);
                    float p2 = (s[g][2][0] + s[g][2][1]) + (s[g][2][2] + s[g][2][3]);
                    float p3 = (s[g][3][0] + s[g][3][1]) + (s[g][3][2] + s[g][3][3]);
                    lpart[g] += (p0 + p1) + (p2 + p3);

                    unsigned upk[4][2];
#pragma unroll
                    for (int n = 0; n < 4; ++n) {
                        asm("v_cvt_pk_bf16_f32 %0, %1, %2"
                            : "=v"(upk[n][0]) : "v"(s[g][n][0]), "v"(s[g][n][1]));
                        asm("v_cvt_pk_bf16_f32 %0, %1, %2"
                            : "=v"(upk[n][1]) : "v"(s[g][n][2]), "v"(s[g][n][3]));
                    }
                    // group all-to-all: after swap32+swap16 on (A,B)=(u[2kk],u[2kk+1]):
                    //   A' = [A_g0, A_g2, B_g0, B_g2]  (b=0 slot, k = 8*lq + 0..3)
                    //   B' = [A_g1, A_g3, B_g1, B_g3]  (b=1 slot, k = 8*lq + 4..7)
#pragma unroll
                    for (int kk = 0; kk < 2; ++kk) {
                        unsigned x0 = upk[2 * kk][0], y0 = upk[2 * kk + 1][0];
                        unsigned x1 = upk[2 * kk][1], y1 = upk[2 * kk + 1][1];
                        asm("v_permlane32_swap_b32 %0, %1" : "+v"(x0), "+v"(y0));
                        asm("v_permlane32_swap_b32 %0, %1" : "+v"(x1), "+v"(y1));
                        asm("v_permlane16_swap_b32 %0, %1" : "+v"(x0), "+v"(y0));
                        asm("v_permlane16_swap_b32 %0, %1" : "+v"(x1), "+v"(y1));
                        union { unsigned u4[4]; short8 s8; } pk;
                        pk.u4[0] = x0; pk.u4[1] = x1; pk.u4[2] = y0; pk.u4[3] = y1;
                        pf[g][kk] = pk.s8;
                    }
                }

                // O += P V : V fragments read once, reused by both q groups
                short8 vf[4][2];
#pragma unroll
                for (int kk = 0; kk < 2; ++kk) {
                    int psw = ((sub * 8 + kk * 4 + lq) ^ (lr & 7)) * 8;
#pragma unroll
                    for (int dt = 0; dt < 4; ++dt)
                        vf[dt][kk] = *reinterpret_cast<const short8*>(
                            Vc + (dt * 16 + lr) * 128 + psw);
                }
#pragma unroll
                for (int g = 0; g < 2; ++g)
#pragma unroll
                    for (int kk = 0; kk < 2; ++kk)
#pragma unroll
                        for (int dt = 0; dt < 4; ++dt)
                            o[g][dt] = mfma16(pf[g][kk], vf[dt][kk], o[g][dt]);
            }

            buf ^= 1;
        }

        // epilogue: l lives per-lane for q=lr; reduce across the 4 lq groups,
        // then redistribute inv to the C-layout rows (q = lq*4 + r).
#pragma unroll
        for (int g = 0; g < 2; ++g) {
            float l = lpart[g];
            l += __shfl_xor(l, 16);
            l += __shfl_xor(l, 32);
            float inv = 1.0f / l;
#pragma unroll
            for (int r = 0; r < 4; ++r) {
                float invr = __shfl(inv, (lane & 48) | (lq * 4 + r));
                int t = q0 + w * 32 + g * 16 + lq * 4 + r;
#pragma unroll
                for (int dt = 0; dt < 4; ++dt) {
                    int d = dt * 16 + lr;
                    ctx[((size_t)(b * T_SEQ + t)) * C_DIM + h * HD + d] =
                        __float2bfloat16(o[g][dt][r] * invr);
                }
            }
        }
    }
}

// ---------------------------------------------------------------- output GEMM
// grid (8, 64), XCD-swizzled like gemm_qkv.
__global__ __launch_bounds__(256, 3) void gemm_out_kernel(
    const bf16_t* __restrict__ Actx, const bf16_t* __restrict__ WoT,
    const float* __restrict__ bo, float* __restrict__ out) {
    __shared__ bf16_t As[128 * 64];
    __shared__ bf16_t Bs[128 * 64];
    int tid = threadIdx.x, wave = tid >> 6, lane = tid & 63;

    int f    = (int)blockIdx.x + ((int)blockIdx.y << 3);
    int xcd  = f & 7;
    int s    = f >> 3;          // 0..63
    int rloc = s & 7;           // A-panel: fastest
    int colp = s >> 3;          // 0..7
    int row0 = (xcd * 8 + rloc) * 128;
    int col0 = colp * 128;

    floatx4 acc[4][4] = {};
    gemm_mainloop(Actx + (size_t)row0 * C_DIM, WoT + (size_t)col0 * C_DIM, As, Bs, acc, wave, lane);
    int lr = lane & 15, lq = lane >> 4;
    int wr = (wave >> 1) * 64, wc = (wave & 1) * 64;
#pragma unroll
    for (int nt = 0; nt < 4; ++nt) {
        int col = col0 + wc + nt * 16 + lr;
        float bvv = bo[col];
#pragma unroll
        for (int m = 0; m < 4; ++m)
#pragma unroll
            for (int r = 0; r < 4; ++r) {
                int rowg = row0 + wr + m * 16 + lq * 4 + r;
                out[(size_t)rowg * C_DIM + col] = acc[m][nt][r] + bvv;
            }
    }
}

// ---------------------------------------------------------------- launcher
extern "C" void kernel_launch(void* const* d_in, const int* in_sizes, int n_in,
                              void* d_out, int out_size, void* d_ws, size_t ws_size,
                              hipStream_t stream) {
    const float* x  = (const float*)d_in[0];
    const float* Wq = (const float*)d_in[1];
    const float* bq = (const float*)d_in[2];
    const float* Wk = (const float*)d_in[3];
    const float* bk = (const float*)d_in[4];
    const float* Wv = (const float*)d_in[5];
    const float* bv = (const float*)d_in[6];
    const float* Wo = (const float*)d_in[7];
    const float* bo = (const float*)d_in[8];
    float* out = (float*)d_out;

    char* ws = (char*)d_ws;
    bf16_t* xb  = (bf16_t*)ws; ws += (size_t)M_ROWS * C_DIM * 2;   // 16 MB
    bf16_t* WqT = (bf16_t*)ws; ws += (size_t)C_DIM * C_DIM * 2;    //  2 MB
    bf16_t* WkT = (bf16_t*)ws; ws += (size_t)C_DIM * C_DIM * 2;
    bf16_t* WvT = (bf16_t*)ws; ws += (size_t)C_DIM * C_DIM * 2;
    bf16_t* WoT = (bf16_t*)ws; ws += (size_t)C_DIM * C_DIM * 2;
    bf16_t* Qb  = (bf16_t*)ws; ws += (size_t)M_ROWS * C_DIM * 2;   // [B,H,T,D]
    bf16_t* Kb  = (bf16_t*)ws; ws += (size_t)M_ROWS * C_DIM * 2;   // [B,H,T,D]
    bf16_t* Vtb = (bf16_t*)ws; ws += (size_t)M_ROWS * C_DIM * 2;   // [B,H,D,T]
    bf16_t* ctx = (bf16_t*)ws; ws += (size_t)M_ROWS * C_DIM * 2;   // [B,T,C]

    convert_x_kernel<<<(M_ROWS * C_DIM / 4) / 256, 256, 0, stream>>>(x, xb);
    transpose_cvt_kernel<<<dim3(32, 32, 4), dim3(32, 8), 0, stream>>>(
        Wq, Wk, Wv, Wo, WqT, WkT, WvT, WoT);
    gemm_qkv_kernel<<<dim3(8, 64, 3), 256, 0, stream>>>(
        xb, WqT, WkT, WvT, bq, bk, bv, Qb, Kb, Vtb);
    attn_kernel<<<dim3(8, 64), 256, 0, stream>>>(Qb, Kb, Vtb, ctx);
    gemm_out_kernel<<<dim3(8, 64), 256, 0, stream>>>(ctx, WoT, bo, out);
}